// Round 1
// 1161.783 us; speedup vs baseline: 1.3784x; 1.3784x over previous
//
#include <hip/hip_runtime.h>
#include <math.h>

#define N_RES 256
#define DIM   128
#define NN    (N_RES * N_RES)                 // 65536 rows per batch
static const size_t NNDf = (size_t)NN * DIM;  // 8,388,608 floats per tensor per batch

typedef __attribute__((ext_vector_type(8))) short bf16x8;   // 8 bf16 = 4 VGPRs
typedef __attribute__((ext_vector_type(4))) float f32x4;

__device__ __forceinline__ float sigmoidf_(float x) { return 1.f / (1.f + __expf(-x)); }

__device__ __forceinline__ unsigned short f32_bf16(float x) {
    unsigned u = __float_as_uint(x);
    return (unsigned short)((u + 0x7FFFu + ((u >> 16) & 1u)) >> 16);   // RNE
}
__device__ __forceinline__ float bf16_f32(unsigned short h) {
    return __uint_as_float(((unsigned)h) << 16);
}

// ---------------------------------------------------------------------------
// Prep: convert 6 weight matrices (row-major [o][k], 128x128 fp32) into
// fragment-ordered split-bf16: hi/lo arrays laid out
//   [(m*8 + nt)*4 + kt][lane][8]  with lane l holding
//   W[o0 + (l&15)][kt*32 + (l>>4)*8 + j]   (o0 = nt*16)
// so k_lin/k_out B-operand loads are lane-linear 16B reads.
// m order: 0=wpa 1=wga 2=wpb 3=wgb 4=wop 5=wog
// ---------------------------------------------------------------------------
__global__ void k_prep(const float* __restrict__ w0, const float* __restrict__ w1,
                       const float* __restrict__ w2, const float* __restrict__ w3,
                       const float* __restrict__ w4, const float* __restrict__ w5,
                       unsigned short* __restrict__ wh, unsigned short* __restrict__ wl)
{
    int idx = blockIdx.x * 256 + threadIdx.x;      // 0 .. 6*16384-1
    int m   = idx >> 14;
    int rem = idx & 16383;
    int o = rem >> 7, k = rem & 127;
    const float* W = (m == 0) ? w0 : (m == 1) ? w1 : (m == 2) ? w2
                   : (m == 3) ? w3 : (m == 4) ? w4 : w5;
    float v = W[o * 128 + k];
    unsigned short hi = f32_bf16(v);
    unsigned short lo = f32_bf16(v - bf16_f32(hi));
    int nt = o >> 4, kt = k >> 5;
    int lane = (o & 15) + (((k >> 3) & 3) << 4);
    int j = k & 7;
    size_t dst = (((size_t)(m * 8 + nt) * 4 + (size_t)kt) * 64 + (size_t)lane) * 8 + (size_t)j;
    wh[dst] = hi;
    wl[dst] = lo;
}

// ---------------------------------------------------------------------------
// K1 (MFMA): zl = LN(z); a = sig(zl@wga^T+bga)*(zl@wpa^T+bpa); bb likewise.
// 64 rows per block, 4 waves; split-bf16 3-pass MFMA (Ah*Bh + Ah*Bl + Al*Bh).
// LDS holds A-fragments in fragment order:
//   region(wv, kt) at byte  wv*4224 + kt*1056  (1056-stride de-conflicts the
//   LN-phase writes; reads are base + lane*16, perfectly linear).
// ---------------------------------------------------------------------------
__global__ __launch_bounds__(256, 2) void k_lin(
    const float* __restrict__ z,
    const float* __restrict__ g_in, const float* __restrict__ b_in,
    const unsigned short* __restrict__ wh, const unsigned short* __restrict__ wl,
    const float* __restrict__ bpa, const float* __restrict__ bga,
    const float* __restrict__ bpb, const float* __restrict__ bgb,
    float* __restrict__ a_out, float* __restrict__ b_out, int b0)
{
    __shared__ alignas(16) unsigned char sA[2 * 16896];   // hi | lo, 33 KB
    int t = threadIdx.x;
    size_t lrow0 = (size_t)blockIdx.x * 64;          // chunk-local row base
    size_t zrow0 = (size_t)b0 * NN + lrow0;          // absolute z row base

    // --- LN + split to bf16 hi/lo, stored fragment-ordered ---
    {
        int r = t >> 2, part = t & 3;
        const float4* src = (const float4*)(z + (zrow0 + r) * (size_t)DIM + part * 32);
        float4 vv[8];
        float sum = 0.f, sq = 0.f;
#pragma unroll
        for (int i = 0; i < 8; ++i) {
            float4 v = src[i];
            vv[i] = v;
            sum += v.x + v.y + v.z + v.w;
            sq  += v.x * v.x + v.y * v.y + v.z * v.z + v.w * v.w;
        }
        sum += __shfl_xor(sum, 1); sum += __shfl_xor(sum, 2);
        sq  += __shfl_xor(sq, 1);  sq  += __shfl_xor(sq, 2);
        float mm  = sum * (1.f / 128.f);
        float var = sq * (1.f / 128.f) - mm * mm;
        float rs  = rsqrtf(var + 1e-5f);
        unsigned char* bh = sA + (r >> 4) * 4224 + part * 1056 + (r & 15) * 16;
#pragma unroll
        for (int i = 0; i < 8; ++i) {
            int c = part * 32 + i * 4;
            float4 v = vv[i];
            float4 g4 = *(const float4*)&g_in[c];
            float4 b4 = *(const float4*)&b_in[c];
            float y0 = (v.x - mm) * rs * g4.x + b4.x;
            float y1 = (v.y - mm) * rs * g4.y + b4.y;
            float y2 = (v.z - mm) * rs * g4.z + b4.z;
            float y3 = (v.w - mm) * rs * g4.w + b4.w;
            unsigned short h0 = f32_bf16(y0), h1 = f32_bf16(y1);
            unsigned short h2 = f32_bf16(y2), h3 = f32_bf16(y3);
            ushort4 hv = make_ushort4(h0, h1, h2, h3);
            ushort4 lv = make_ushort4(f32_bf16(y0 - bf16_f32(h0)),
                                      f32_bf16(y1 - bf16_f32(h1)),
                                      f32_bf16(y2 - bf16_f32(h2)),
                                      f32_bf16(y3 - bf16_f32(h3)));
            int off = (i >> 1) * 256 + (i & 1) * 8;
            *(ushort4*)(bh + off)         = hv;
            *(ushort4*)(bh + 16896 + off) = lv;
        }
    }
    __syncthreads();

    // --- MFMA phase: wave wv owns rows lrow0 + wv*16 .. +15 ---
    int wv = t >> 6, lane = t & 63;
    int col = lane & 15, kgrp = lane >> 4;

    bf16x8 ah[4], al[4];
    const unsigned char* abase = sA + wv * 4224 + (size_t)lane * 16;
#pragma unroll
    for (int kt = 0; kt < 4; ++kt) {
        ah[kt] = *(const bf16x8*)(abase + kt * 1056);
        al[kt] = *(const bf16x8*)(abase + 16896 + kt * 1056);
    }

    size_t rbase = (lrow0 + (size_t)wv * 16 + (size_t)kgrp * 4) * (size_t)DIM;

#pragma unroll
    for (int pair = 0; pair < 2; ++pair) {
        const int mg = pair ? 3 : 1;                 // wgb : wga
        const int mp = pair ? 2 : 0;                 // wpb : wpa
        const float* Bg = pair ? bgb : bga;
        const float* Bp = pair ? bpb : bpa;
        float* op = pair ? b_out : a_out;
        for (int nt = 0; nt < 8; ++nt) {
            float bgv = Bg[nt * 16 + col];
            float bpv = Bp[nt * 16 + col];
            f32x4 accg = {bgv, bgv, bgv, bgv};
            f32x4 accp = {bpv, bpv, bpv, bpv};
            size_t goff = ((size_t)(mg * 8 + nt) * 4 * 64 + (size_t)lane) * 8;
            size_t poff = ((size_t)(mp * 8 + nt) * 4 * 64 + (size_t)lane) * 8;
#pragma unroll
            for (int kt = 0; kt < 4; ++kt) {
                bf16x8 bgh = *(const bf16x8*)(wh + goff + kt * 512);
                bf16x8 bgl = *(const bf16x8*)(wl + goff + kt * 512);
                bf16x8 bph = *(const bf16x8*)(wh + poff + kt * 512);
                bf16x8 bpl = *(const bf16x8*)(wl + poff + kt * 512);
                accg = __builtin_amdgcn_mfma_f32_16x16x32_bf16(ah[kt], bgh, accg, 0, 0, 0);
                accg = __builtin_amdgcn_mfma_f32_16x16x32_bf16(ah[kt], bgl, accg, 0, 0, 0);
                accg = __builtin_amdgcn_mfma_f32_16x16x32_bf16(al[kt], bgh, accg, 0, 0, 0);
                accp = __builtin_amdgcn_mfma_f32_16x16x32_bf16(ah[kt], bph, accp, 0, 0, 0);
                accp = __builtin_amdgcn_mfma_f32_16x16x32_bf16(ah[kt], bpl, accp, 0, 0, 0);
                accp = __builtin_amdgcn_mfma_f32_16x16x32_bf16(al[kt], bph, accp, 0, 0, 0);
            }
#pragma unroll
            for (int r = 0; r < 4; ++r) {
                op[rbase + (size_t)r * DIM + nt * 16 + col] = accp[r] * sigmoidf_(accg[r]);
            }
        }
    }
}

// ---------------------------------------------------------------------------
// K2: tri[b,i,j,d] = sum_k a[b,i,k,d] * bb[b,j,k,d]   (unchanged this round)
// ---------------------------------------------------------------------------
__global__ __launch_bounds__(256, 2) void k_tri(
    const float* __restrict__ a, const float* __restrict__ b,
    float* __restrict__ tri)
{
    __shared__ float sA[32 * 132];
    __shared__ float sB[32 * 132];
    int t = threadIdx.x;
    int b_l  = blockIdx.x >> 6;
    int tile = blockIdx.x & 63;
    int it = tile >> 3, jt = tile & 7;
    int d0 = blockIdx.y * 16;

    int dg = t & 3;
    int ig = (t >> 2) & 7;
    int jg = t >> 5;

    int p = t >> 2, f = t & 3;
    int kl = p & 7, ih = p >> 3;

    float4 acc[4][4];
#pragma unroll
    for (int ii = 0; ii < 4; ++ii)
#pragma unroll
        for (int jj = 0; jj < 4; ++jj) acc[ii][jj] = make_float4(0.f, 0.f, 0.f, 0.f);

    size_t abase = ((size_t)b_l * NN + (size_t)(it * 32) * N_RES) * DIM;
    size_t bbase = ((size_t)b_l * NN + (size_t)(jt * 32) * N_RES) * DIM;

    for (int k0 = 0; k0 < N_RES; k0 += 8) {
        __syncthreads();
#pragma unroll
        for (int itr = 0; itr < 4; ++itr) {
            int il = itr * 8 + ih;
            size_t goff = (size_t)il * N_RES * DIM + (size_t)(k0 + kl) * DIM + d0 + f * 4;
            *(float4*)&sA[il * 132 + kl * 16 + f * 4] = *(const float4*)&a[abase + goff];
            *(float4*)&sB[il * 132 + kl * 16 + f * 4] = *(const float4*)&b[bbase + goff];
        }
        __syncthreads();
#pragma unroll
        for (int k = 0; k < 8; ++k) {
            float4 av[4], bv[4];
#pragma unroll
            for (int ii = 0; ii < 4; ++ii) av[ii] = *(const float4*)&sA[(ig * 4 + ii) * 132 + k * 16 + dg * 4];
#pragma unroll
            for (int jj = 0; jj < 4; ++jj) bv[jj] = *(const float4*)&sB[(jg * 4 + jj) * 132 + k * 16 + dg * 4];
#pragma unroll
            for (int ii = 0; ii < 4; ++ii)
#pragma unroll
                for (int jj = 0; jj < 4; ++jj) {
                    acc[ii][jj].x += av[ii].x * bv[jj].x;
                    acc[ii][jj].y += av[ii].y * bv[jj].y;
                    acc[ii][jj].z += av[ii].z * bv[jj].z;
                    acc[ii][jj].w += av[ii].w * bv[jj].w;
                }
        }
    }

    size_t obase = (size_t)b_l * NN;
#pragma unroll
    for (int ii = 0; ii < 4; ++ii)
#pragma unroll
        for (int jj = 0; jj < 4; ++jj) {
            int i_g = it * 32 + ig * 4 + ii;
            int j_g = jt * 32 + jg * 4 + jj;
            *(float4*)&tri[(obase + (size_t)i_g * N_RES + j_g) * DIM + d0 + dg * 4] = acc[ii][jj];
        }
}

// ---------------------------------------------------------------------------
// K3: out = sig(LN(z)@wog^T+bog) * (LN(tri,g_out,b_out)@wop^T+bop)  (unchanged)
// ---------------------------------------------------------------------------
__device__ __forceinline__ void load_ln_t(const float* __restrict__ X, size_t row0,
                                          const float* __restrict__ g,
                                          const float* __restrict__ b,
                                          float* sXt, int t)
{
    int r = t >> 2, part = t & 3;
    const float4* src = (const float4*)(X + (row0 + r) * (size_t)DIM + part * 32);
    float4 vv[8];
    float sum = 0.f, sq = 0.f;
#pragma unroll
    for (int i = 0; i < 8; ++i) {
        float4 v = src[i];
        vv[i] = v;
        sum += v.x + v.y + v.z + v.w;
        sq  += v.x * v.x + v.y * v.y + v.z * v.z + v.w * v.w;
    }
    sum += __shfl_xor(sum, 1); sum += __shfl_xor(sum, 2);
    sq  += __shfl_xor(sq, 1);  sq  += __shfl_xor(sq, 2);
    float m   = sum * (1.f / 128.f);
    float var = sq * (1.f / 128.f) - m * m;
    float rs  = rsqrtf(var + 1e-5f);
#pragma unroll
    for (int i = 0; i < 8; ++i) {
        int c = part * 32 + i * 4;
        float4 v = vv[i];
        sXt[(c + 0) * 68 + r] = (v.x - m) * rs * g[c + 0] + b[c + 0];
        sXt[(c + 1) * 68 + r] = (v.y - m) * rs * g[c + 1] + b[c + 1];
        sXt[(c + 2) * 68 + r] = (v.z - m) * rs * g[c + 2] + b[c + 2];
        sXt[(c + 3) * 68 + r] = (v.w - m) * rs * g[c + 3] + b[c + 3];
    }
}

__device__ __forceinline__ void load_w_t(const float* __restrict__ W, int o0,
                                         float* sWt, int t)
{
    int o_l = t >> 3;
    int kp  = (t & 7) * 16;
    const float4* src = (const float4*)(W + (size_t)(o0 + o_l) * DIM + kp);
#pragma unroll
    for (int i = 0; i < 4; ++i) {
        float4 v = src[i];
        int k = kp + i * 4;
        sWt[(k + 0) * 36 + o_l] = v.x;
        sWt[(k + 1) * 36 + o_l] = v.y;
        sWt[(k + 2) * 36 + o_l] = v.z;
        sWt[(k + 3) * 36 + o_l] = v.w;
    }
}

__device__ __forceinline__ void matmul_slab(const float* sXt, const float* sWt,
                                            int tr, int tc, float acc[4][2])
{
#pragma unroll 8
    for (int k = 0; k < 128; ++k) {
        float4 a4 = *(const float4*)&sXt[k * 68 + tr * 4];
        float2 w2 = *(const float2*)&sWt[k * 36 + tc * 2];
        acc[0][0] += a4.x * w2.x; acc[0][1] += a4.x * w2.y;
        acc[1][0] += a4.y * w2.x; acc[1][1] += a4.y * w2.y;
        acc[2][0] += a4.z * w2.x; acc[2][1] += a4.z * w2.y;
        acc[3][0] += a4.w * w2.x; acc[3][1] += a4.w * w2.y;
    }
}

__global__ __launch_bounds__(256, 2) void k_out(
    const float* __restrict__ tri, const float* __restrict__ z,
    const float* __restrict__ g_in, const float* __restrict__ b_in,
    const float* __restrict__ g_out, const float* __restrict__ b_out,
    const float* __restrict__ wop, const float* __restrict__ bop,
    const float* __restrict__ wog, const float* __restrict__ bog,
    float* __restrict__ out, int b0)
{
    __shared__ float sXt[128 * 68];
    __shared__ float sWt[128 * 36];
    int t = threadIdx.x;
    size_t lrow0 = (size_t)blockIdx.x * 64;
    size_t zrow0 = (size_t)b0 * NN + lrow0;
    int tr = t >> 4, tc = t & 15;

    load_ln_t(z, zrow0, g_in, b_in, sXt, t);
    float gate[4][4][2];
#pragma unroll
    for (int slab = 0; slab < 4; ++slab) {
        int o0 = slab * 32;
        __syncthreads();
        load_w_t(wog, o0, sWt, t);
        __syncthreads();
        float acc[4][2];
#pragma unroll
        for (int ii = 0; ii < 4; ++ii) { acc[ii][0] = bog[o0 + tc * 2]; acc[ii][1] = bog[o0 + tc * 2 + 1]; }
        matmul_slab(sXt, sWt, tr, tc, acc);
#pragma unroll
        for (int ii = 0; ii < 4; ++ii) { gate[slab][ii][0] = acc[ii][0]; gate[slab][ii][1] = acc[ii][1]; }
    }

    __syncthreads();
    load_ln_t(tri, lrow0, g_out, b_out, sXt, t);
#pragma unroll
    for (int slab = 0; slab < 4; ++slab) {
        int o0 = slab * 32;
        __syncthreads();
        load_w_t(wop, o0, sWt, t);
        __syncthreads();
        float acc[4][2];
#pragma unroll
        for (int ii = 0; ii < 4; ++ii) { acc[ii][0] = bop[o0 + tc * 2]; acc[ii][1] = bop[o0 + tc * 2 + 1]; }
        matmul_slab(sXt, sWt, tr, tc, acc);
#pragma unroll
        for (int ii = 0; ii < 4; ++ii) {
            float2 o;
            o.x = acc[ii][0] * sigmoidf_(gate[slab][ii][0]);
            o.y = acc[ii][1] * sigmoidf_(gate[slab][ii][1]);
            *(float2*)&out[(zrow0 + tr * 4 + ii) * (size_t)DIM + o0 + tc * 2] = o;
        }
    }
}

extern "C" void kernel_launch(void* const* d_in, const int* in_sizes, int n_in,
                              void* d_out, int out_size, void* d_ws, size_t ws_size,
                              hipStream_t stream)
{
    const float* z    = (const float*)d_in[0];
    const float* g_in = (const float*)d_in[1];
    const float* b_in = (const float*)d_in[2];
    const float* wpa  = (const float*)d_in[3];
    const float* bpa  = (const float*)d_in[4];
    const float* wga  = (const float*)d_in[5];
    const float* bga  = (const float*)d_in[6];
    const float* wpb  = (const float*)d_in[7];
    const float* bpb  = (const float*)d_in[8];
    const float* wgb  = (const float*)d_in[9];
    const float* bgb  = (const float*)d_in[10];
    const float* gout = (const float*)d_in[11];
    const float* bout = (const float*)d_in[12];
    const float* wop  = (const float*)d_in[13];
    const float* bop  = (const float*)d_in[14];
    const float* wog  = (const float*)d_in[15];
    const float* bog  = (const float*)d_in[16];
    float* out = (float*)d_out;
    float* ws  = (float*)d_ws;

    // Workspace layout:
    //   [0)           wh: 6*16384 bf16 hi  (196,608 B)
    //   [196608)      wl: 6*16384 bf16 lo  (196,608 B)
    //   [393216)      per-batch fp32 scratch: a, bb, tri
    unsigned short* wh = (unsigned short*)ws;
    unsigned short* wl = wh + 6 * 16384;
    float* sbase = ws + (2 * 6 * 16384 * sizeof(unsigned short)) / sizeof(float);

    const size_t per_batch_bytes = 3 * NNDf * sizeof(float);
    size_t avail = ws_size - 2 * 6 * 16384 * sizeof(unsigned short);
    int nb = (int)(avail / per_batch_bytes);
    if (nb < 1) nb = 1;
    if (nb > 4) nb = 4;
    float* aw = sbase;
    float* bw = sbase + (size_t)nb * NNDf;
    float* tw = sbase + 2 * (size_t)nb * NNDf;

    // One-time weight conversion to fragment-ordered split-bf16.
    k_prep<<<384, 256, 0, stream>>>(wpa, wga, wpb, wgb, wop, wog, wh, wl);

    for (int b0 = 0; b0 < 4; b0 += nb) {
        int nbc = (4 - b0) < nb ? (4 - b0) : nb;
        k_lin<<<nbc * 1024, 256, 0, stream>>>(z, g_in, b_in, wh, wl,
                                              bpa, bga, bpb, bgb, aw, bw, b0);
        k_tri<<<dim3(nbc * 64, 8), 256, 0, stream>>>(aw, bw, tw);
        k_out<<<nbc * 1024, 256, 0, stream>>>(tw, z, g_in, b_in, gout, bout,
                                              wop, bop, wog, bog, out, b0);
    }
}

// Round 2
// 801.416 us; speedup vs baseline: 1.9982x; 1.4497x over previous
//
#include <hip/hip_runtime.h>
#include <math.h>

#define N_RES 256
#define DIM   128
#define NN    (N_RES * N_RES)                 // 65536 rows per batch
static const size_t NNDf = (size_t)NN * DIM;  // 8,388,608 elements per tensor per batch

typedef __attribute__((ext_vector_type(8))) short bf16x8;   // 8 bf16 = 4 VGPRs
typedef __attribute__((ext_vector_type(4))) float f32x4;

__device__ __forceinline__ float sigmoidf_(float x) { return 1.f / (1.f + __expf(-x)); }

__device__ __forceinline__ unsigned short f32_bf16(float x) {
    unsigned u = __float_as_uint(x);
    return (unsigned short)((u + 0x7FFFu + ((u >> 16) & 1u)) >> 16);   // RNE
}
__device__ __forceinline__ float bf16_f32(unsigned short h) {
    return __uint_as_float(((unsigned)h) << 16);
}

// ---------------------------------------------------------------------------
// Prep: 6 weight matrices -> fragment-ordered split-bf16 (hi/lo).
// lane l of frag (m, nt, kt) holds W[nt*16 + (l&15)][kt*32 + (l>>4)*8 + j].
// m order: 0=wpa 1=wga 2=wpb 3=wgb 4=wop 5=wog
// ---------------------------------------------------------------------------
__global__ void k_prep(const float* __restrict__ w0, const float* __restrict__ w1,
                       const float* __restrict__ w2, const float* __restrict__ w3,
                       const float* __restrict__ w4, const float* __restrict__ w5,
                       unsigned short* __restrict__ wh, unsigned short* __restrict__ wl)
{
    int idx = blockIdx.x * 256 + threadIdx.x;      // 0 .. 6*16384-1
    int m   = idx >> 14;
    int rem = idx & 16383;
    int o = rem >> 7, k = rem & 127;
    const float* W = (m == 0) ? w0 : (m == 1) ? w1 : (m == 2) ? w2
                   : (m == 3) ? w3 : (m == 4) ? w4 : w5;
    float v = W[o * 128 + k];
    unsigned short hi = f32_bf16(v);
    unsigned short lo = f32_bf16(v - bf16_f32(hi));
    int nt = o >> 4, kt = k >> 5;
    int lane = (o & 15) + (((k >> 3) & 3) << 4);
    int j = k & 7;
    size_t dst = (((size_t)(m * 8 + nt) * 4 + (size_t)kt) * 64 + (size_t)lane) * 8 + (size_t)j;
    wh[dst] = hi;
    wl[dst] = lo;
}

// ---------------------------------------------------------------------------
// K1: zl = LN(z); a = sig(zl@wga^T+bga)*(zl@wpa^T+bpa); bb likewise.
// Split-bf16 3-pass MFMA. Outputs stored split-bf16 in [bc][d][i][k] layout
// (k = contraction index of the triangle einsum, contiguous).
// ---------------------------------------------------------------------------
__global__ __launch_bounds__(256, 2) void k_lin(
    const float* __restrict__ z,
    const float* __restrict__ g_in, const float* __restrict__ b_in,
    const unsigned short* __restrict__ wh, const unsigned short* __restrict__ wl,
    const float* __restrict__ bpa, const float* __restrict__ bga,
    const float* __restrict__ bpb, const float* __restrict__ bgb,
    unsigned short* __restrict__ Ah, unsigned short* __restrict__ Al,
    unsigned short* __restrict__ Bh, unsigned short* __restrict__ Bl, int b0)
{
    __shared__ alignas(16) unsigned char sA[2 * 16896];   // hi | lo, 33 KB
    int t = threadIdx.x;
    size_t lrow0 = (size_t)blockIdx.x * 64;          // chunk-local row base
    int bc   = (int)(lrow0 >> 16);                   // chunk-local batch
    int rowb = (int)(lrow0 & 65535);                 // row within batch
    size_t zrow0 = (size_t)b0 * NN + lrow0;          // absolute z row base

    // --- LN + split to bf16 hi/lo, stored fragment-ordered ---
    {
        int r = t >> 2, part = t & 3;
        const float4* src = (const float4*)(z + (zrow0 + r) * (size_t)DIM + part * 32);
        float4 vv[8];
        float sum = 0.f, sq = 0.f;
#pragma unroll
        for (int i = 0; i < 8; ++i) {
            float4 v = src[i];
            vv[i] = v;
            sum += v.x + v.y + v.z + v.w;
            sq  += v.x * v.x + v.y * v.y + v.z * v.z + v.w * v.w;
        }
        sum += __shfl_xor(sum, 1); sum += __shfl_xor(sum, 2);
        sq  += __shfl_xor(sq, 1);  sq  += __shfl_xor(sq, 2);
        float mm  = sum * (1.f / 128.f);
        float var = sq * (1.f / 128.f) - mm * mm;
        float rs  = rsqrtf(var + 1e-5f);
        unsigned char* bh = sA + (r >> 4) * 4224 + part * 1056 + (r & 15) * 16;
#pragma unroll
        for (int i = 0; i < 8; ++i) {
            int c = part * 32 + i * 4;
            float4 v = vv[i];
            float4 g4 = *(const float4*)&g_in[c];
            float4 b4 = *(const float4*)&b_in[c];
            float y0 = (v.x - mm) * rs * g4.x + b4.x;
            float y1 = (v.y - mm) * rs * g4.y + b4.y;
            float y2 = (v.z - mm) * rs * g4.z + b4.z;
            float y3 = (v.w - mm) * rs * g4.w + b4.w;
            unsigned short h0 = f32_bf16(y0), h1 = f32_bf16(y1);
            unsigned short h2 = f32_bf16(y2), h3 = f32_bf16(y3);
            ushort4 hv = make_ushort4(h0, h1, h2, h3);
            ushort4 lv = make_ushort4(f32_bf16(y0 - bf16_f32(h0)),
                                      f32_bf16(y1 - bf16_f32(h1)),
                                      f32_bf16(y2 - bf16_f32(h2)),
                                      f32_bf16(y3 - bf16_f32(h3)));
            int off = (i >> 1) * 256 + (i & 1) * 8;
            *(ushort4*)(bh + off)         = hv;
            *(ushort4*)(bh + 16896 + off) = lv;
        }
    }
    __syncthreads();

    // --- MFMA phase ---
    int wv = t >> 6, lane = t & 63;
    int col = lane & 15, kgrp = lane >> 4;

    bf16x8 ah[4], al[4];
    const unsigned char* abase = sA + wv * 4224 + (size_t)lane * 16;
#pragma unroll
    for (int kt = 0; kt < 4; ++kt) {
        ah[kt] = *(const bf16x8*)(abase + kt * 1056);
        al[kt] = *(const bf16x8*)(abase + 16896 + kt * 1056);
    }

    int rowbase = rowb + wv * 16 + kgrp * 4;

#pragma unroll
    for (int pair = 0; pair < 2; ++pair) {
        const int mg = pair ? 3 : 1;                 // wgb : wga
        const int mp = pair ? 2 : 0;                 // wpb : wpa
        const float* Bg = pair ? bgb : bga;
        const float* Bp = pair ? bpb : bpa;
        unsigned short* oh = pair ? Bh : Ah;
        unsigned short* ol = pair ? Bl : Al;
        for (int nt = 0; nt < 8; ++nt) {
            float bgv = Bg[nt * 16 + col];
            float bpv = Bp[nt * 16 + col];
            f32x4 accg = {bgv, bgv, bgv, bgv};
            f32x4 accp = {bpv, bpv, bpv, bpv};
            size_t goff = ((size_t)(mg * 8 + nt) * 4 * 64 + (size_t)lane) * 8;
            size_t poff = ((size_t)(mp * 8 + nt) * 4 * 64 + (size_t)lane) * 8;
#pragma unroll
            for (int kt = 0; kt < 4; ++kt) {
                bf16x8 bgh = *(const bf16x8*)(wh + goff + kt * 512);
                bf16x8 bgl = *(const bf16x8*)(wl + goff + kt * 512);
                bf16x8 bph = *(const bf16x8*)(wh + poff + kt * 512);
                bf16x8 bpl = *(const bf16x8*)(wl + poff + kt * 512);
                accg = __builtin_amdgcn_mfma_f32_16x16x32_bf16(ah[kt], bgh, accg, 0, 0, 0);
                accg = __builtin_amdgcn_mfma_f32_16x16x32_bf16(ah[kt], bgl, accg, 0, 0, 0);
                accg = __builtin_amdgcn_mfma_f32_16x16x32_bf16(al[kt], bgh, accg, 0, 0, 0);
                accp = __builtin_amdgcn_mfma_f32_16x16x32_bf16(ah[kt], bph, accp, 0, 0, 0);
                accp = __builtin_amdgcn_mfma_f32_16x16x32_bf16(ah[kt], bpl, accp, 0, 0, 0);
                accp = __builtin_amdgcn_mfma_f32_16x16x32_bf16(al[kt], bph, accp, 0, 0, 0);
            }
            // store split-bf16 to [bc][d][row] plane, rows contiguous
            size_t plane = (((size_t)bc * 128) + (size_t)(nt * 16 + col)) << 16;
            ushort4 hv, lv;
#pragma unroll
            for (int r = 0; r < 4; ++r) {
                float val = accp[r] * sigmoidf_(accg[r]);
                unsigned short h = f32_bf16(val);
                ((unsigned short*)&hv)[r] = h;
                ((unsigned short*)&lv)[r] = f32_bf16(val - bf16_f32(h));
            }
            *(ushort4*)&oh[plane + rowbase] = hv;
            *(ushort4*)&ol[plane + rowbase] = lv;
        }
    }
}

// ---------------------------------------------------------------------------
// K2 (MFMA): per (bc,d) plane: C[i][j] = sum_k A[i][k]*B[j][k], 256x256x256,
// split-bf16 3-pass. 128x128 tile per block, 4 waves x 64x64, BK=32.
// LDS tiles stored fragment-ordered (lane-linear, conflict-free).
// Output tri in [bc][d][i*256+j] fp32 (coalesced 64B frag-row writes).
// ---------------------------------------------------------------------------
__global__ __launch_bounds__(256, 2) void k_tri(
    const unsigned short* __restrict__ Ah, const unsigned short* __restrict__ Al,
    const unsigned short* __restrict__ Bh, const unsigned short* __restrict__ Bl,
    float* __restrict__ tri)
{
    __shared__ alignas(16) unsigned short sAh[4096], sAl[4096], sBh[4096], sBl[4096]; // 32 KB
    int t = threadIdx.x;
    int bid = blockIdx.x;
    int tile = bid & 3;
    int pd = bid >> 2;                     // bc*128 + d
    int it = tile >> 1, jt = tile & 1;
    size_t pbase = (size_t)pd << 16;
    const unsigned short* pAh = Ah + pbase;
    const unsigned short* pAl = Al + pbase;
    const unsigned short* pBh = Bh + pbase;
    const unsigned short* pBl = Bl + pbase;
    int i0 = it * 128, j0 = jt * 128;

    int sr = t >> 2, sc = t & 3;           // staging: row, 16B-chunk
    int wv = t >> 6, lane = t & 63;
    int wr = wv >> 1, wc = wv & 1;         // wave quadrant
    int kgrp = lane >> 4, col = lane & 15;

    f32x4 acc[4][4];
#pragma unroll
    for (int mi = 0; mi < 4; ++mi)
#pragma unroll
        for (int ni = 0; ni < 4; ++ni) { f32x4 zf = {0.f, 0.f, 0.f, 0.f}; acc[mi][ni] = zf; }

    for (int k0 = 0; k0 < 256; k0 += 32) {
        __syncthreads();
#pragma unroll
        for (int rr = 0; rr < 2; ++rr) {
            int row = sr + rr * 64;
            int dst = (row >> 4) * 512 + (((row & 15) + 16 * sc) << 3);
            size_t aoff = (size_t)(i0 + row) * 256 + (size_t)(k0 + sc * 8);
            size_t boff = (size_t)(j0 + row) * 256 + (size_t)(k0 + sc * 8);
            *(uint4*)&sAh[dst] = *(const uint4*)&pAh[aoff];
            *(uint4*)&sAl[dst] = *(const uint4*)&pAl[aoff];
            *(uint4*)&sBh[dst] = *(const uint4*)&pBh[boff];
            *(uint4*)&sBl[dst] = *(const uint4*)&pBl[boff];
        }
        __syncthreads();
        bf16x8 a_h[4], a_l[4], b_h[4], b_l[4];
#pragma unroll
        for (int mi = 0; mi < 4; ++mi) {
            a_h[mi] = *(const bf16x8*)&sAh[(wr * 4 + mi) * 512 + lane * 8];
            a_l[mi] = *(const bf16x8*)&sAl[(wr * 4 + mi) * 512 + lane * 8];
        }
#pragma unroll
        for (int ni = 0; ni < 4; ++ni) {
            b_h[ni] = *(const bf16x8*)&sBh[(wc * 4 + ni) * 512 + lane * 8];
            b_l[ni] = *(const bf16x8*)&sBl[(wc * 4 + ni) * 512 + lane * 8];
        }
#pragma unroll
        for (int mi = 0; mi < 4; ++mi)
#pragma unroll
            for (int ni = 0; ni < 4; ++ni) {
                acc[mi][ni] = __builtin_amdgcn_mfma_f32_16x16x32_bf16(a_h[mi], b_h[ni], acc[mi][ni], 0, 0, 0);
                acc[mi][ni] = __builtin_amdgcn_mfma_f32_16x16x32_bf16(a_h[mi], b_l[ni], acc[mi][ni], 0, 0, 0);
                acc[mi][ni] = __builtin_amdgcn_mfma_f32_16x16x32_bf16(a_l[mi], b_h[ni], acc[mi][ni], 0, 0, 0);
            }
    }

    float* op = tri + pbase;
#pragma unroll
    for (int mi = 0; mi < 4; ++mi) {
        int ig0 = i0 + wr * 64 + mi * 16 + kgrp * 4;
#pragma unroll
        for (int ni = 0; ni < 4; ++ni) {
            int jg = j0 + wc * 64 + ni * 16 + col;
#pragma unroll
            for (int r4 = 0; r4 < 4; ++r4)
                op[(size_t)(ig0 + r4) * 256 + jg] = acc[mi][ni][r4];
        }
    }
}

// ---------------------------------------------------------------------------
// K3 (MFMA): out = sig(LN(z)@wog^T+bog) * (LN(tri)@wop^T+bop)
// Phase A: LN(z) -> sA frags -> gate GEMM (held in regs).
// Phase B: LN(tri from [d][ij] planes) -> sA frags -> proj GEMM -> combine.
// ---------------------------------------------------------------------------
__global__ __launch_bounds__(256, 2) void k_out(
    const float* __restrict__ tri, const float* __restrict__ z,
    const float* __restrict__ g_in, const float* __restrict__ b_in,
    const float* __restrict__ g_out, const float* __restrict__ b_out,
    const unsigned short* __restrict__ wh, const unsigned short* __restrict__ wl,
    const float* __restrict__ bop, const float* __restrict__ bog,
    float* __restrict__ out, int b0)
{
    __shared__ alignas(16) unsigned char sA[2 * 16896];
    int t = threadIdx.x;
    size_t lrow0 = (size_t)blockIdx.x * 64;
    int bc   = (int)(lrow0 >> 16);
    int rowb = (int)(lrow0 & 65535);
    size_t zrow0 = (size_t)b0 * NN + lrow0;

    // --- Phase A: LN(z) -> sA (fragment-ordered hi/lo) ---
    {
        int r = t >> 2, part = t & 3;
        const float4* src = (const float4*)(z + (zrow0 + r) * (size_t)DIM + part * 32);
        float4 vv[8];
        float sum = 0.f, sq = 0.f;
#pragma unroll
        for (int i = 0; i < 8; ++i) {
            float4 v = src[i];
            vv[i] = v;
            sum += v.x + v.y + v.z + v.w;
            sq  += v.x * v.x + v.y * v.y + v.z * v.z + v.w * v.w;
        }
        sum += __shfl_xor(sum, 1); sum += __shfl_xor(sum, 2);
        sq  += __shfl_xor(sq, 1);  sq  += __shfl_xor(sq, 2);
        float mm  = sum * (1.f / 128.f);
        float var = sq * (1.f / 128.f) - mm * mm;
        float rs  = rsqrtf(var + 1e-5f);
        unsigned char* bh = sA + (r >> 4) * 4224 + part * 1056 + (r & 15) * 16;
#pragma unroll
        for (int i = 0; i < 8; ++i) {
            int c = part * 32 + i * 4;
            float4 v = vv[i];
            float4 g4 = *(const float4*)&g_in[c];
            float4 b4 = *(const float4*)&b_in[c];
            float y0 = (v.x - mm) * rs * g4.x + b4.x;
            float y1 = (v.y - mm) * rs * g4.y + b4.y;
            float y2 = (v.z - mm) * rs * g4.z + b4.z;
            float y3 = (v.w - mm) * rs * g4.w + b4.w;
            unsigned short h0 = f32_bf16(y0), h1 = f32_bf16(y1);
            unsigned short h2 = f32_bf16(y2), h3 = f32_bf16(y3);
            ushort4 hv = make_ushort4(h0, h1, h2, h3);
            ushort4 lv = make_ushort4(f32_bf16(y0 - bf16_f32(h0)),
                                      f32_bf16(y1 - bf16_f32(h1)),
                                      f32_bf16(y2 - bf16_f32(h2)),
                                      f32_bf16(y3 - bf16_f32(h3)));
            int off = (i >> 1) * 256 + (i & 1) * 8;
            *(ushort4*)(bh + off)         = hv;
            *(ushort4*)(bh + 16896 + off) = lv;
        }
    }
    __syncthreads();

    int wv = t >> 6, lane = t & 63;
    int col = lane & 15, kgrp = lane >> 4;

    // --- gate = LN(z) @ wog^T + bog (held in regs) ---
    f32x4 gate[8];
    {
        bf16x8 ah[4], al[4];
        const unsigned char* abase = sA + wv * 4224 + (size_t)lane * 16;
#pragma unroll
        for (int kt = 0; kt < 4; ++kt) {
            ah[kt] = *(const bf16x8*)(abase + kt * 1056);
            al[kt] = *(const bf16x8*)(abase + 16896 + kt * 1056);
        }
        for (int nt = 0; nt < 8; ++nt) {
            float bv = bog[nt * 16 + col];
            f32x4 g = {bv, bv, bv, bv};
            size_t goff = ((size_t)(5 * 8 + nt) * 4 * 64 + (size_t)lane) * 8;
#pragma unroll
            for (int kt = 0; kt < 4; ++kt) {
                bf16x8 bh8 = *(const bf16x8*)(wh + goff + kt * 512);
                bf16x8 bl8 = *(const bf16x8*)(wl + goff + kt * 512);
                g = __builtin_amdgcn_mfma_f32_16x16x32_bf16(ah[kt], bh8, g, 0, 0, 0);
                g = __builtin_amdgcn_mfma_f32_16x16x32_bf16(ah[kt], bl8, g, 0, 0, 0);
                g = __builtin_amdgcn_mfma_f32_16x16x32_bf16(al[kt], bh8, g, 0, 0, 0);
            }
            gate[nt] = g;
        }
    }
    __syncthreads();   // all waves done reading sA before overwrite

    // --- Phase B: LN(tri) from [bc][d][ij] planes -> sA frags ---
    {
        int r = t >> 2, part = t & 3;
        const float* tp = tri + (((size_t)(bc * 128 + part * 32)) << 16) + rowb + r;
        float vv[32];
        float sum = 0.f, sq = 0.f;
#pragma unroll
        for (int i = 0; i < 32; ++i) {
            float v = tp[(size_t)i << 16];
            vv[i] = v; sum += v; sq += v * v;
        }
        sum += __shfl_xor(sum, 1); sum += __shfl_xor(sum, 2);
        sq  += __shfl_xor(sq, 1);  sq  += __shfl_xor(sq, 2);
        float mm  = sum * (1.f / 128.f);
        float var = sq * (1.f / 128.f) - mm * mm;
        float rs  = rsqrtf(var + 1e-5f);
        unsigned char* bh = sA + (r >> 4) * 4224 + part * 1056 + (r & 15) * 16;
#pragma unroll
        for (int g4 = 0; g4 < 8; ++g4) {
            ushort4 hv, lv;
#pragma unroll
            for (int e = 0; e < 4; ++e) {
                int i = g4 * 4 + e;
                int c = part * 32 + i;
                float y = (vv[i] - mm) * rs * g_out[c] + b_out[c];
                unsigned short h = f32_bf16(y);
                ((unsigned short*)&hv)[e] = h;
                ((unsigned short*)&lv)[e] = f32_bf16(y - bf16_f32(h));
            }
            int off = (g4 >> 1) * 256 + (g4 & 1) * 8;
            *(ushort4*)(bh + off)         = hv;
            *(ushort4*)(bh + 16896 + off) = lv;
        }
    }
    __syncthreads();

    // --- proj = LN(tri) @ wop^T + bop ; combine & write ---
    {
        bf16x8 th[4], tl[4];
        const unsigned char* abase = sA + wv * 4224 + (size_t)lane * 16;
#pragma unroll
        for (int kt = 0; kt < 4; ++kt) {
            th[kt] = *(const bf16x8*)(abase + kt * 1056);
            tl[kt] = *(const bf16x8*)(abase + 16896 + kt * 1056);
        }
        size_t rbase = (zrow0 + (size_t)wv * 16 + (size_t)kgrp * 4) * (size_t)DIM;
        for (int nt = 0; nt < 8; ++nt) {
            float bv = bop[nt * 16 + col];
            f32x4 p = {bv, bv, bv, bv};
            size_t poff = ((size_t)(4 * 8 + nt) * 4 * 64 + (size_t)lane) * 8;
#pragma unroll
            for (int kt = 0; kt < 4; ++kt) {
                bf16x8 bh8 = *(const bf16x8*)(wh + poff + kt * 512);
                bf16x8 bl8 = *(const bf16x8*)(wl + poff + kt * 512);
                p = __builtin_amdgcn_mfma_f32_16x16x32_bf16(th[kt], bh8, p, 0, 0, 0);
                p = __builtin_amdgcn_mfma_f32_16x16x32_bf16(th[kt], bl8, p, 0, 0, 0);
                p = __builtin_amdgcn_mfma_f32_16x16x32_bf16(tl[kt], bh8, p, 0, 0, 0);
            }
#pragma unroll
            for (int r4 = 0; r4 < 4; ++r4)
                out[rbase + (size_t)r4 * DIM + nt * 16 + col] = p[r4] * sigmoidf_(gate[nt][r4]);
        }
    }
}

extern "C" void kernel_launch(void* const* d_in, const int* in_sizes, int n_in,
                              void* d_out, int out_size, void* d_ws, size_t ws_size,
                              hipStream_t stream)
{
    const float* z    = (const float*)d_in[0];
    const float* g_in = (const float*)d_in[1];
    const float* b_in = (const float*)d_in[2];
    const float* wpa  = (const float*)d_in[3];
    const float* bpa  = (const float*)d_in[4];
    const float* wga  = (const float*)d_in[5];
    const float* bga  = (const float*)d_in[6];
    const float* wpb  = (const float*)d_in[7];
    const float* bpb  = (const float*)d_in[8];
    const float* wgb  = (const float*)d_in[9];
    const float* bgb  = (const float*)d_in[10];
    const float* gout = (const float*)d_in[11];
    const float* bout = (const float*)d_in[12];
    const float* wop  = (const float*)d_in[13];
    const float* bop  = (const float*)d_in[14];
    const float* wog  = (const float*)d_in[15];
    const float* bog  = (const float*)d_in[16];
    float* out = (float*)d_out;

    // Workspace layout:
    //   wh, wl: 6*16384 ushorts each (fragment-ordered weights)
    //   Ah, Al, Bh, Bl: nb * NNDf ushorts each ([bc][d][i][k] split-bf16)
    //   T: nb * NNDf floats ([bc][d][i*256+j] fp32)
    unsigned short* wh = (unsigned short*)d_ws;
    unsigned short* wl = wh + 6 * 16384;
    unsigned short* sb = wl + 6 * 16384;

    const size_t per_batch_bytes = 12 * NNDf;   // 8*NNDf (bf16 x4) + 4*NNDf (tri fp32)
    size_t avail = ws_size - 2 * 6 * 16384 * sizeof(unsigned short);
    int nb = (int)(avail / per_batch_bytes);
    if (nb < 1) nb = 1;
    if (nb > 4) nb = 4;

    unsigned short* Ah = sb;
    unsigned short* Al = Ah + (size_t)nb * NNDf;
    unsigned short* Bh = Al + (size_t)nb * NNDf;
    unsigned short* Bl = Bh + (size_t)nb * NNDf;
    float* T = (float*)(Bl + (size_t)nb * NNDf);

    k_prep<<<384, 256, 0, stream>>>(wpa, wga, wpb, wgb, wop, wog, wh, wl);

    for (int b0 = 0; b0 < 4; b0 += nb) {
        int nbc = (4 - b0) < nb ? (4 - b0) : nb;
        k_lin<<<nbc * 1024, 256, 0, stream>>>(z, g_in, b_in, wh, wl,
                                              bpa, bga, bpb, bgb, Ah, Al, Bh, Bl, b0);
        k_tri<<<nbc * 512, 256, 0, stream>>>(Ah, Al, Bh, Bl, T);
        k_out<<<nbc * 1024, 256, 0, stream>>>(T, z, g_in, b_in, gout, bout,
                                              wh, wl, bop, bog, out, b0);
    }
}

// Round 6
// 737.609 us; speedup vs baseline: 2.1710x; 1.0865x over previous
//
#include <hip/hip_runtime.h>
#include <math.h>

#define N_RES 256
#define DIM   128
#define NN    (N_RES * N_RES)                 // 65536 rows per batch
static const size_t NNDf = (size_t)NN * DIM;  // 8,388,608 elements per tensor per batch

typedef __attribute__((ext_vector_type(8))) short bf16x8;   // 8 bf16 = 4 VGPRs
typedef __attribute__((ext_vector_type(4))) float f32x4;

__device__ __forceinline__ float sigmoidf_(float x) { return 1.f / (1.f + __expf(-x)); }

__device__ __forceinline__ unsigned short f32_bf16(float x) {
    unsigned u = __float_as_uint(x);
    return (unsigned short)((u + 0x7FFFu + ((u >> 16) & 1u)) >> 16);   // RNE
}
__device__ __forceinline__ float bf16_f32(unsigned short h) {
    return __uint_as_float(((unsigned)h) << 16);
}

// ---------------------------------------------------------------------------
// Prep: 6 weight matrices -> fragment-ordered split-bf16 (hi/lo).
// lane l of frag (m, nt, kt) holds W[nt*16 + (l&15)][kt*32 + (l>>4)*8 + j].
// m order: 0=wpa 1=wga 2=wpb 3=wgb 4=wop 5=wog
// ---------------------------------------------------------------------------
__global__ void k_prep(const float* __restrict__ w0, const float* __restrict__ w1,
                       const float* __restrict__ w2, const float* __restrict__ w3,
                       const float* __restrict__ w4, const float* __restrict__ w5,
                       unsigned short* __restrict__ wh, unsigned short* __restrict__ wl)
{
    int idx = blockIdx.x * 256 + threadIdx.x;      // 0 .. 6*16384-1
    int m   = idx >> 14;
    int rem = idx & 16383;
    int o = rem >> 7, k = rem & 127;
    const float* W = (m == 0) ? w0 : (m == 1) ? w1 : (m == 2) ? w2
                   : (m == 3) ? w3 : (m == 4) ? w4 : w5;
    float v = W[o * 128 + k];
    unsigned short hi = f32_bf16(v);
    unsigned short lo = f32_bf16(v - bf16_f32(hi));
    int nt = o >> 4, kt = k >> 5;
    int lane = (o & 15) + (((k >> 3) & 3) << 4);
    int j = k & 7;
    size_t dst = (((size_t)(m * 8 + nt) * 4 + (size_t)kt) * 64 + (size_t)lane) * 8 + (size_t)j;
    wh[dst] = hi;
    wl[dst] = lo;
}

// ---------------------------------------------------------------------------
// K1: zl = LN(z); a = sig(zl@wga^T+bga)*(zl@wpa^T+bpa); bb likewise.
// Round-2 proven structure: 64 rows/block, split-bf16 3-pass MFMA.
// Outputs split-bf16 in [bc][d][i][k] layout (contraction contiguous).
// ---------------------------------------------------------------------------
__global__ __launch_bounds__(256, 2) void k_lin(
    const float* __restrict__ z,
    const float* __restrict__ g_in, const float* __restrict__ b_in,
    const unsigned short* __restrict__ wh, const unsigned short* __restrict__ wl,
    const float* __restrict__ bpa, const float* __restrict__ bga,
    const float* __restrict__ bpb, const float* __restrict__ bgb,
    unsigned short* __restrict__ Ah, unsigned short* __restrict__ Al,
    unsigned short* __restrict__ Bh, unsigned short* __restrict__ Bl, int b0)
{
    __shared__ alignas(16) unsigned char sA[2 * 16896];   // hi | lo, 33 KB
    int t = threadIdx.x;
    size_t lrow0 = (size_t)blockIdx.x * 64;          // chunk-local row base
    int bc   = (int)(lrow0 >> 16);                   // chunk-local batch
    int rowb = (int)(lrow0 & 65535);                 // row within batch
    size_t zrow0 = (size_t)b0 * NN + lrow0;          // absolute z row base

    // --- LN + split to bf16 hi/lo, stored fragment-ordered ---
    {
        int r = t >> 2, part = t & 3;
        const float4* src = (const float4*)(z + (zrow0 + r) * (size_t)DIM + part * 32);
        float4 vv[8];
        float sum = 0.f, sq = 0.f;
#pragma unroll
        for (int i = 0; i < 8; ++i) {
            float4 v = src[i];
            vv[i] = v;
            sum += v.x + v.y + v.z + v.w;
            sq  += v.x * v.x + v.y * v.y + v.z * v.z + v.w * v.w;
        }
        sum += __shfl_xor(sum, 1); sum += __shfl_xor(sum, 2);
        sq  += __shfl_xor(sq, 1);  sq  += __shfl_xor(sq, 2);
        float mm  = sum * (1.f / 128.f);
        float var = sq * (1.f / 128.f) - mm * mm;
        float rs  = rsqrtf(var + 1e-5f);
        unsigned char* bh = sA + (r >> 4) * 4224 + part * 1056 + (r & 15) * 16;
#pragma unroll
        for (int i = 0; i < 8; ++i) {
            int c = part * 32 + i * 4;
            float4 v = vv[i];
            float4 g4 = *(const float4*)&g_in[c];
            float4 b4 = *(const float4*)&b_in[c];
            float y0 = (v.x - mm) * rs * g4.x + b4.x;
            float y1 = (v.y - mm) * rs * g4.y + b4.y;
            float y2 = (v.z - mm) * rs * g4.z + b4.z;
            float y3 = (v.w - mm) * rs * g4.w + b4.w;
            unsigned short h0 = f32_bf16(y0), h1 = f32_bf16(y1);
            unsigned short h2 = f32_bf16(y2), h3 = f32_bf16(y3);
            ushort4 hv = make_ushort4(h0, h1, h2, h3);
            ushort4 lv = make_ushort4(f32_bf16(y0 - bf16_f32(h0)),
                                      f32_bf16(y1 - bf16_f32(h1)),
                                      f32_bf16(y2 - bf16_f32(h2)),
                                      f32_bf16(y3 - bf16_f32(h3)));
            int off = (i >> 1) * 256 + (i & 1) * 8;
            *(ushort4*)(bh + off)         = hv;
            *(ushort4*)(bh + 16896 + off) = lv;
        }
    }
    __syncthreads();

    // --- MFMA phase ---
    int wv = t >> 6, lane = t & 63;
    int col = lane & 15, kgrp = lane >> 4;

    bf16x8 ah[4], al[4];
    const unsigned char* abase = sA + wv * 4224 + (size_t)lane * 16;
#pragma unroll
    for (int kt = 0; kt < 4; ++kt) {
        ah[kt] = *(const bf16x8*)(abase + kt * 1056);
        al[kt] = *(const bf16x8*)(abase + 16896 + kt * 1056);
    }

    int rowbase = rowb + wv * 16 + kgrp * 4;

#pragma unroll
    for (int pair = 0; pair < 2; ++pair) {
        const int mg = pair ? 3 : 1;                 // wgb : wga
        const int mp = pair ? 2 : 0;                 // wpb : wpa
        const float* Bg = pair ? bgb : bga;
        const float* Bp = pair ? bpb : bpa;
        unsigned short* oh = pair ? Bh : Ah;
        unsigned short* ol = pair ? Bl : Al;
        for (int nt = 0; nt < 8; ++nt) {
            float bgv = Bg[nt * 16 + col];
            float bpv = Bp[nt * 16 + col];
            f32x4 accg = {bgv, bgv, bgv, bgv};
            f32x4 accp = {bpv, bpv, bpv, bpv};
            size_t goff = ((size_t)(mg * 8 + nt) * 4 * 64 + (size_t)lane) * 8;
            size_t poff = ((size_t)(mp * 8 + nt) * 4 * 64 + (size_t)lane) * 8;
#pragma unroll
            for (int kt = 0; kt < 4; ++kt) {
                bf16x8 bgh = *(const bf16x8*)(wh + goff + kt * 512);
                bf16x8 bgl = *(const bf16x8*)(wl + goff + kt * 512);
                bf16x8 bph = *(const bf16x8*)(wh + poff + kt * 512);
                bf16x8 bpl = *(const bf16x8*)(wl + poff + kt * 512);
                accg = __builtin_amdgcn_mfma_f32_16x16x32_bf16(ah[kt], bgh, accg, 0, 0, 0);
                accg = __builtin_amdgcn_mfma_f32_16x16x32_bf16(ah[kt], bgl, accg, 0, 0, 0);
                accg = __builtin_amdgcn_mfma_f32_16x16x32_bf16(al[kt], bgh, accg, 0, 0, 0);
                accp = __builtin_amdgcn_mfma_f32_16x16x32_bf16(ah[kt], bph, accp, 0, 0, 0);
                accp = __builtin_amdgcn_mfma_f32_16x16x32_bf16(ah[kt], bpl, accp, 0, 0, 0);
                accp = __builtin_amdgcn_mfma_f32_16x16x32_bf16(al[kt], bph, accp, 0, 0, 0);
            }
            // store split-bf16 to [bc][d][row] plane, rows contiguous
            size_t plane = (((size_t)bc * 128) + (size_t)(nt * 16 + col)) << 16;
            ushort4 hv, lv;
#pragma unroll
            for (int r = 0; r < 4; ++r) {
                float val = accp[r] * sigmoidf_(accg[r]);
                unsigned short h = f32_bf16(val);
                ((unsigned short*)&hv)[r] = h;
                ((unsigned short*)&lv)[r] = f32_bf16(val - bf16_f32(h));
            }
            *(ushort4*)&oh[plane + rowbase] = hv;
            *(ushort4*)&ol[plane + rowbase] = lv;
        }
    }
}

// ---------------------------------------------------------------------------
// K2 (MFMA): per (bc,d) plane: C[i][j] = sum_k A[i][k]*B[j][k], 256x256x256,
// split-bf16 3-pass. 128x128 tile per block, 4 waves x 64x64, BK=32.
// Round-2 proven 2-barrier structure. NEW (mapping-only, numerics-free):
// XCD-chunked blockIdx swizzle so the 4 tiles of one (bc,d) plane land on the
// same XCD's L2 (default round-robin spreads them over 4 XCDs -> 4x re-fetch).
// ---------------------------------------------------------------------------
__global__ __launch_bounds__(256, 2) void k_tri(
    const unsigned short* __restrict__ Ah, const unsigned short* __restrict__ Al,
    const unsigned short* __restrict__ Bh, const unsigned short* __restrict__ Bl,
    float* __restrict__ tri)
{
    __shared__ alignas(16) unsigned short sAh[4096], sAl[4096], sBh[4096], sBl[4096]; // 32 KB
    int t = threadIdx.x;
    // XCD swizzle: grid = nbc*512 (always % 8 == 0) -> bijective chunked map.
    // HW: XCD = blockIdx % 8; assign work w so each XCD gets a contiguous range.
    int cpx = gridDim.x >> 3;
    int bid = (blockIdx.x & 7) * cpx + (blockIdx.x >> 3);
    int tile = bid & 3;
    int pd = bid >> 2;                     // bc*128 + d
    int it = tile >> 1, jt = tile & 1;
    size_t pbase = (size_t)pd << 16;
    const unsigned short* pAh = Ah + pbase;
    const unsigned short* pAl = Al + pbase;
    const unsigned short* pBh = Bh + pbase;
    const unsigned short* pBl = Bl + pbase;
    int i0 = it * 128, j0 = jt * 128;

    int sr = t >> 2, sc = t & 3;           // staging: row, 16B-chunk
    int wv = t >> 6, lane = t & 63;
    int wr = wv >> 1, wc = wv & 1;         // wave quadrant
    int kgrp = lane >> 4, col = lane & 15;

    f32x4 acc[4][4];
#pragma unroll
    for (int mi = 0; mi < 4; ++mi)
#pragma unroll
        for (int ni = 0; ni < 4; ++ni) { f32x4 zf = {0.f, 0.f, 0.f, 0.f}; acc[mi][ni] = zf; }

    for (int k0 = 0; k0 < 256; k0 += 32) {
        __syncthreads();
#pragma unroll
        for (int rr = 0; rr < 2; ++rr) {
            int row = sr + rr * 64;
            int dst = (row >> 4) * 512 + (((row & 15) + 16 * sc) << 3);
            size_t aoff = (size_t)(i0 + row) * 256 + (size_t)(k0 + sc * 8);
            size_t boff = (size_t)(j0 + row) * 256 + (size_t)(k0 + sc * 8);
            *(uint4*)&sAh[dst] = *(const uint4*)&pAh[aoff];
            *(uint4*)&sAl[dst] = *(const uint4*)&pAl[aoff];
            *(uint4*)&sBh[dst] = *(const uint4*)&pBh[boff];
            *(uint4*)&sBl[dst] = *(const uint4*)&pBl[boff];
        }
        __syncthreads();
        bf16x8 a_h[4], a_l[4], b_h[4], b_l[4];
#pragma unroll
        for (int mi = 0; mi < 4; ++mi) {
            a_h[mi] = *(const bf16x8*)&sAh[(wr * 4 + mi) * 512 + lane * 8];
            a_l[mi] = *(const bf16x8*)&sAl[(wr * 4 + mi) * 512 + lane * 8];
        }
#pragma unroll
        for (int ni = 0; ni < 4; ++ni) {
            b_h[ni] = *(const bf16x8*)&sBh[(wc * 4 + ni) * 512 + lane * 8];
            b_l[ni] = *(const bf16x8*)&sBl[(wc * 4 + ni) * 512 + lane * 8];
        }
#pragma unroll
        for (int mi = 0; mi < 4; ++mi)
#pragma unroll
            for (int ni = 0; ni < 4; ++ni) {
                acc[mi][ni] = __builtin_amdgcn_mfma_f32_16x16x32_bf16(a_h[mi], b_h[ni], acc[mi][ni], 0, 0, 0);
                acc[mi][ni] = __builtin_amdgcn_mfma_f32_16x16x32_bf16(a_h[mi], b_l[ni], acc[mi][ni], 0, 0, 0);
                acc[mi][ni] = __builtin_amdgcn_mfma_f32_16x16x32_bf16(a_l[mi], b_h[ni], acc[mi][ni], 0, 0, 0);
            }
    }

    float* op = tri + pbase;
#pragma unroll
    for (int mi = 0; mi < 4; ++mi) {
        int ig0 = i0 + wr * 64 + mi * 16 + kgrp * 4;
#pragma unroll
        for (int ni = 0; ni < 4; ++ni) {
            int jg = j0 + wc * 64 + ni * 16 + col;
#pragma unroll
            for (int r4 = 0; r4 < 4; ++r4)
                op[(size_t)(ig0 + r4) * 256 + jg] = acc[mi][ni][r4];
        }
    }
}

// ---------------------------------------------------------------------------
// K3 (MFMA): out = sig(LN(z)@wog^T+bog) * (LN(tri)@wop^T+bop)
// Round-2 proven structure (weights direct from global; deterministic).
// ---------------------------------------------------------------------------
__global__ __launch_bounds__(256, 2) void k_out(
    const float* __restrict__ tri, const float* __restrict__ z,
    const float* __restrict__ g_in, const float* __restrict__ b_in,
    const float* __restrict__ g_out, const float* __restrict__ b_out,
    const unsigned short* __restrict__ wh, const unsigned short* __restrict__ wl,
    const float* __restrict__ bop, const float* __restrict__ bog,
    float* __restrict__ out, int b0)
{
    __shared__ alignas(16) unsigned char sA[2 * 16896];
    int t = threadIdx.x;
    size_t lrow0 = (size_t)blockIdx.x * 64;
    int bc   = (int)(lrow0 >> 16);
    int rowb = (int)(lrow0 & 65535);
    size_t zrow0 = (size_t)b0 * NN + lrow0;

    // --- Phase A: LN(z) -> sA (fragment-ordered hi/lo) ---
    {
        int r = t >> 2, part = t & 3;
        const float4* src = (const float4*)(z + (zrow0 + r) * (size_t)DIM + part * 32);
        float4 vv[8];
        float sum = 0.f, sq = 0.f;
#pragma unroll
        for (int i = 0; i < 8; ++i) {
            float4 v = src[i];
            vv[i] = v;
            sum += v.x + v.y + v.z + v.w;
            sq  += v.x * v.x + v.y * v.y + v.z * v.z + v.w * v.w;
        }
        sum += __shfl_xor(sum, 1); sum += __shfl_xor(sum, 2);
        sq  += __shfl_xor(sq, 1);  sq  += __shfl_xor(sq, 2);
        float mm  = sum * (1.f / 128.f);
        float var = sq * (1.f / 128.f) - mm * mm;
        float rs  = rsqrtf(var + 1e-5f);
        unsigned char* bh = sA + (r >> 4) * 4224 + part * 1056 + (r & 15) * 16;
#pragma unroll
        for (int i = 0; i < 8; ++i) {
            int c = part * 32 + i * 4;
            float4 v = vv[i];
            float4 g4 = *(const float4*)&g_in[c];
            float4 b4 = *(const float4*)&b_in[c];
            float y0 = (v.x - mm) * rs * g4.x + b4.x;
            float y1 = (v.y - mm) * rs * g4.y + b4.y;
            float y2 = (v.z - mm) * rs * g4.z + b4.z;
            float y3 = (v.w - mm) * rs * g4.w + b4.w;
            unsigned short h0 = f32_bf16(y0), h1 = f32_bf16(y1);
            unsigned short h2 = f32_bf16(y2), h3 = f32_bf16(y3);
            ushort4 hv = make_ushort4(h0, h1, h2, h3);
            ushort4 lv = make_ushort4(f32_bf16(y0 - bf16_f32(h0)),
                                      f32_bf16(y1 - bf16_f32(h1)),
                                      f32_bf16(y2 - bf16_f32(h2)),
                                      f32_bf16(y3 - bf16_f32(h3)));
            int off = (i >> 1) * 256 + (i & 1) * 8;
            *(ushort4*)(bh + off)         = hv;
            *(ushort4*)(bh + 16896 + off) = lv;
        }
    }
    __syncthreads();

    int wv = t >> 6, lane = t & 63;
    int col = lane & 15, kgrp = lane >> 4;

    // --- gate = LN(z) @ wog^T + bog (held in regs) ---
    f32x4 gate[8];
    {
        bf16x8 ah[4], al[4];
        const unsigned char* abase = sA + wv * 4224 + (size_t)lane * 16;
#pragma unroll
        for (int kt = 0; kt < 4; ++kt) {
            ah[kt] = *(const bf16x8*)(abase + kt * 1056);
            al[kt] = *(const bf16x8*)(abase + 16896 + kt * 1056);
        }
        for (int nt = 0; nt < 8; ++nt) {
            float bv = bog[nt * 16 + col];
            f32x4 g = {bv, bv, bv, bv};
            size_t goff = ((size_t)(5 * 8 + nt) * 4 * 64 + (size_t)lane) * 8;
#pragma unroll
            for (int kt = 0; kt < 4; ++kt) {
                bf16x8 bh8 = *(const bf16x8*)(wh + goff + kt * 512);
                bf16x8 bl8 = *(const bf16x8*)(wl + goff + kt * 512);
                g = __builtin_amdgcn_mfma_f32_16x16x32_bf16(ah[kt], bh8, g, 0, 0, 0);
                g = __builtin_amdgcn_mfma_f32_16x16x32_bf16(ah[kt], bl8, g, 0, 0, 0);
                g = __builtin_amdgcn_mfma_f32_16x16x32_bf16(al[kt], bh8, g, 0, 0, 0);
            }
            gate[nt] = g;
        }
    }
    __syncthreads();   // all waves done reading sA before overwrite

    // --- Phase B: LN(tri) from [bc][d][ij] planes -> sA frags ---
    {
        int r = t >> 2, part = t & 3;
        const float* tp = tri + (((size_t)(bc * 128 + part * 32)) << 16) + rowb + r;
        float vv[32];
        float sum = 0.f, sq = 0.f;
#pragma unroll
        for (int i = 0; i < 32; ++i) {
            float v = tp[(size_t)i << 16];
            vv[i] = v; sum += v; sq += v * v;
        }
        sum += __shfl_xor(sum, 1); sum += __shfl_xor(sum, 2);
        sq  += __shfl_xor(sq, 1);  sq  += __shfl_xor(sq, 2);
        float mm  = sum * (1.f / 128.f);
        float var = sq * (1.f / 128.f) - mm * mm;
        float rs  = rsqrtf(var + 1e-5f);
        unsigned char* bh = sA + (r >> 4) * 4224 + part * 1056 + (r & 15) * 16;
#pragma unroll
        for (int g4 = 0; g4 < 8; ++g4) {
            ushort4 hv, lv;
#pragma unroll
            for (int e = 0; e < 4; ++e) {
                int i = g4 * 4 + e;
                int c = part * 32 + i;
                float y = (vv[i] - mm) * rs * g_out[c] + b_out[c];
                unsigned short h = f32_bf16(y);
                ((unsigned short*)&hv)[e] = h;
                ((unsigned short*)&lv)[e] = f32_bf16(y - bf16_f32(h));
            }
            int off = (g4 >> 1) * 256 + (g4 & 1) * 8;
            *(ushort4*)(bh + off)         = hv;
            *(ushort4*)(bh + 16896 + off) = lv;
        }
    }
    __syncthreads();

    // --- proj = LN(tri) @ wop^T + bop ; combine & write ---
    {
        bf16x8 th[4], tl[4];
        const unsigned char* abase = sA + wv * 4224 + (size_t)lane * 16;
#pragma unroll
        for (int kt = 0; kt < 4; ++kt) {
            th[kt] = *(const bf16x8*)(abase + kt * 1056);
            tl[kt] = *(const bf16x8*)(abase + 16896 + kt * 1056);
        }
        size_t rbase = (zrow0 + (size_t)wv * 16 + (size_t)kgrp * 4) * (size_t)DIM;
        for (int nt = 0; nt < 8; ++nt) {
            float bv = bop[nt * 16 + col];
            f32x4 p = {bv, bv, bv, bv};
            size_t poff = ((size_t)(4 * 8 + nt) * 4 * 64 + (size_t)lane) * 8;
#pragma unroll
            for (int kt = 0; kt < 4; ++kt) {
                bf16x8 bh8 = *(const bf16x8*)(wh + poff + kt * 512);
                bf16x8 bl8 = *(const bf16x8*)(wl + poff + kt * 512);
                p = __builtin_amdgcn_mfma_f32_16x16x32_bf16(th[kt], bh8, p, 0, 0, 0);
                p = __builtin_amdgcn_mfma_f32_16x16x32_bf16(th[kt], bl8, p, 0, 0, 0);
                p = __builtin_amdgcn_mfma_f32_16x16x32_bf16(tl[kt], bh8, p, 0, 0, 0);
            }
#pragma unroll
            for (int r4 = 0; r4 < 4; ++r4)
                out[rbase + (size_t)r4 * DIM + nt * 16 + col] = p[r4] * sigmoidf_(gate[nt][r4]);
        }
    }
}

extern "C" void kernel_launch(void* const* d_in, const int* in_sizes, int n_in,
                              void* d_out, int out_size, void* d_ws, size_t ws_size,
                              hipStream_t stream)
{
    const float* z    = (const float*)d_in[0];
    const float* g_in = (const float*)d_in[1];
    const float* b_in = (const float*)d_in[2];
    const float* wpa  = (const float*)d_in[3];
    const float* bpa  = (const float*)d_in[4];
    const float* wga  = (const float*)d_in[5];
    const float* bga  = (const float*)d_in[6];
    const float* wpb  = (const float*)d_in[7];
    const float* bpb  = (const float*)d_in[8];
    const float* wgb  = (const float*)d_in[9];
    const float* bgb  = (const float*)d_in[10];
    const float* gout = (const float*)d_in[11];
    const float* bout = (const float*)d_in[12];
    const float* wop  = (const float*)d_in[13];
    const float* bop  = (const float*)d_in[14];
    const float* wog  = (const float*)d_in[15];
    const float* bog  = (const float*)d_in[16];
    float* out = (float*)d_out;

    unsigned short* wh = (unsigned short*)d_ws;
    unsigned short* wl = wh + 6 * 16384;
    unsigned short* sb = wl + 6 * 16384;

    const size_t per_batch_bytes = 12 * NNDf;   // 8*NNDf (bf16 x4) + 4*NNDf (tri fp32)
    size_t avail = ws_size - 2 * 6 * 16384 * sizeof(unsigned short);
    int nb = (int)(avail / per_batch_bytes);
    if (nb < 1) nb = 1;
    if (nb > 4) nb = 4;

    unsigned short* Ah = sb;
    unsigned short* Al = Ah + (size_t)nb * NNDf;
    unsigned short* Bh = Al + (size_t)nb * NNDf;
    unsigned short* Bl = Bh + (size_t)nb * NNDf;
    float* T = (float*)(Bl + (size_t)nb * NNDf);

    k_prep<<<384, 256, 0, stream>>>(wpa, wga, wpb, wgb, wop, wog, wh, wl);

    for (int b0 = 0; b0 < 4; b0 += nb) {
        int nbc = (4 - b0) < nb ? (4 - b0) : nb;
        k_lin<<<nbc * 1024, 256, 0, stream>>>(z, g_in, b_in, wh, wl,
                                              bpa, bga, bpb, bgb, Ah, Al, Bh, Bl, b0);
        k_tri<<<nbc * 512, 256, 0, stream>>>(Ah, Al, Bh, Bl, T);
        k_out<<<nbc * 1024, 256, 0, stream>>>(T, z, g_in, b_in, gout, bout,
                                              wh, wl, bop, bog, out, b0);
    }
}